// Round 5
// baseline (48.867 us; speedup 1.0000x reference)
//
#include <hip/hip_runtime.h>

#define PAD 8

typedef float f32x4 __attribute__((ext_vector_type(4)));

// out[n,c,y,x] = x[n, c, clamp(y+sy,0,127), clamp(x+sx,0,127)], (sx,sy)=shift[n]-8.
//
// Key fact: (sx,sy) is uniform per block (32 consecutive rows share n). So the
// x-shift is a funnel-shift by a uniform word count: each lane reads two
// ALIGNED float4s from the source row and selects elements by rm = sx&3
// (template-specialized, uniform branch). Edge clamp = per-lane predicates,
// loop-invariant across the 4 row-tiles. No LDS, no barrier.
//
// Clamp correctness: w_i = 4t+sx+i.
//   w_i<=0  -> need in[0];   w_i<=0 implies j0=t+(sx>>2)<=0, so a=row4[0], a.x=in[0].
//   w_i>=127-> need in[127]; implies j1>=32 (or j0>=31 for rm=0), so b(row4[31]).w=in[127].
// Interior: j0=-1 with rm+i>=4 selects b=row4[0] elem rm+i-4 = word rm+i-4 = w_i. OK.
template<int RM>
__device__ __forceinline__ void body(
    const float* __restrict__ xin, float* __restrict__ outbase,
    int ybase, int sy, int j0c, int j1c,
    bool lo0, bool lo1, bool lo2, bool lo3,
    bool hi0, bool hi1, bool hi2, bool hi3,
    int r, int t) {
  constexpr int H = 128, W = 128;
  constexpr int TILES = 4, ROWS = 8;
#pragma unroll
  for (int k = 0; k < TILES; ++k) {
    int y = ybase + k * ROWS + r;
    int ysrc = min(max(y + sy, 0), H - 1);
    const f32x4* __restrict__ row4 = reinterpret_cast<const f32x4*>(xin + ysrc * W);
    f32x4 a = row4[j0c];
    f32x4 b = a;
    if constexpr (RM != 0) b = row4[j1c];
    const float fl = a.x;                          // in[0] when lo fires
    float fh;
    if constexpr (RM == 0) fh = a.w; else fh = b.w;  // in[127] when hi fires
    f32x4 o;
    if constexpr (RM == 0)      { o.x = a.x; o.y = a.y; o.z = a.z; o.w = a.w; }
    else if constexpr (RM == 1) { o.x = a.y; o.y = a.z; o.z = a.w; o.w = b.x; }
    else if constexpr (RM == 2) { o.x = a.z; o.y = a.w; o.z = b.x; o.w = b.y; }
    else                        { o.x = a.w; o.y = b.x; o.z = b.y; o.w = b.z; }
    o.x = lo0 ? fl : (hi0 ? fh : o.x);
    o.y = lo1 ? fl : (hi1 ? fh : o.y);
    o.z = lo2 ? fl : (hi2 ? fh : o.z);
    o.w = lo3 ? fl : (hi3 ? fh : o.w);
    __builtin_nontemporal_store(
        o, reinterpret_cast<f32x4*>(outbase + (size_t)(k * ROWS + r) * W) + t);
  }
}

__global__ __launch_bounds__(256) void shift_aug_kernel(
    const float* __restrict__ x,
    const int* __restrict__ shift,
    float* __restrict__ out,
    int C) {
  constexpr int H = 128, W = 128;
  constexpr int TILES = 4, ROWS = 8;

  const int r = threadIdx.x >> 5;   // 0..7: row within tile
  const int t = threadIdx.x & 31;   // float4 lane within row

  const int base = blockIdx.x * (TILES * ROWS);   // first row of block
  const int nc = base >> 7;                       // row / 128
  const int n  = nc / C;

  const int sx = shift[2 * n + 0] - PAD;
  const int sy = shift[2 * n + 1] - PAD;
  const int ybase = base & (H - 1);

  const float* __restrict__ xin = x + (size_t)nc * H * W;
  float* __restrict__ outbase = out + (size_t)base * W;

  const int s4f = sx >> 2;          // floor(sx/4), uniform
  const int rm  = sx & 3;           // uniform
  const int j0  = t + s4f;
  const int j0c = min(max(j0, 0), 31);
  const int j1c = min(max(j0 + 1, 0), 31);
  const int wb  = 4 * j0 + rm;      // = 4t + sx; w_i = wb + i

  const bool lo0 = (wb + 0) <= 0,  lo1 = (wb + 1) <= 0,
             lo2 = (wb + 2) <= 0,  lo3 = (wb + 3) <= 0;
  const bool hi0 = (wb + 0) >= 127, hi1 = (wb + 1) >= 127,
             hi2 = (wb + 2) >= 127, hi3 = (wb + 3) >= 127;

  switch (rm) {  // uniform branch per block
    case 0: body<0>(xin, outbase, ybase, sy, j0c, j1c, lo0,lo1,lo2,lo3, hi0,hi1,hi2,hi3, r, t); break;
    case 1: body<1>(xin, outbase, ybase, sy, j0c, j1c, lo0,lo1,lo2,lo3, hi0,hi1,hi2,hi3, r, t); break;
    case 2: body<2>(xin, outbase, ybase, sy, j0c, j1c, lo0,lo1,lo2,lo3, hi0,hi1,hi2,hi3, r, t); break;
    default: body<3>(xin, outbase, ybase, sy, j0c, j1c, lo0,lo1,lo2,lo3, hi0,hi1,hi2,hi3, r, t); break;
  }
}

extern "C" void kernel_launch(void* const* d_in, const int* in_sizes, int n_in,
                              void* d_out, int out_size, void* d_ws, size_t ws_size,
                              hipStream_t stream) {
  const float* x     = (const float*)d_in[0];
  const int*   shift = (const int*)d_in[1];
  float*       out   = (float*)d_out;

  const int C = 9, H = 128;
  int N = in_sizes[1] / 2;            // shift is (N,1,1,2) int32
  int nRows = N * C * H;              // 294912
  int blocks = nRows / 32;            // 9216 blocks, 32 rows each

  hipLaunchKernelGGL(shift_aug_kernel, dim3(blocks), dim3(256), 0, stream,
                     x, shift, out, C);
}